// Round 1
// baseline (115.952 us; speedup 1.0000x reference)
//
#include <hip/hip_runtime.h>
#include <hip/hip_bf16.h>
#include <math.h>

#define D 8192
#define NT 256

// ---------- block reduction helpers (256 threads fixed) ----------
__device__ __forceinline__ float block_sum(float v, float* sm) {
    const int t = threadIdx.x;
    sm[t] = v; __syncthreads();
    for (int s = NT / 2; s > 0; s >>= 1) {
        if (t < s) sm[t] += sm[t + s];
        __syncthreads();
    }
    float r = sm[0]; __syncthreads();
    return r;
}

__device__ __forceinline__ float block_max(float v, float* sm) {
    const int t = threadIdx.x;
    sm[t] = v; __syncthreads();
    for (int s = NT / 2; s > 0; s >>= 1) {
        if (t < s) sm[t] = fmaxf(sm[t], sm[t + s]);
        __syncthreads();
    }
    float r = sm[0]; __syncthreads();
    return r;
}

// ---------- K1: per teacher row: top-8, p, gather predictor rows -> g vec + c scalar ----------
__global__ __launch_bounds__(NT) void k_teacher(
    const float* __restrict__ teacher, const float* __restrict__ center,
    const float* __restrict__ pred, const int* __restrict__ epoch_p,
    float* __restrict__ g_ws, float* __restrict__ c_ws)
{
    const int row = blockIdx.x;     // 0..511  (iq = row/256, b = row%256)
    const int t = threadIdx.x;
    __shared__ float sv[NT];
    __shared__ int   si[NT];

    const int e = epoch_p[0];
    const float temp = (e < 30) ? (0.04f + 0.03f * (float)e / 29.0f) : 0.07f;

    // load z = teacher - center into registers (32 per thread, strided float4)
    float z[32];
    const float* trow = teacher + (size_t)row * D;
    #pragma unroll
    for (int i = 0; i < 8; ++i) {
        const int d = i * 1024 + t * 4;
        float4 tv = *(const float4*)(trow + d);
        float4 cv = *(const float4*)(center + d);
        z[i*4+0] = tv.x - cv.x;
        z[i*4+1] = tv.y - cv.y;
        z[i*4+2] = tv.z - cv.z;
        z[i*4+3] = tv.w - cv.w;
    }

    // 8 rounds of global argmax
    float topv[8]; int topd[8];
    #pragma unroll
    for (int k = 0; k < 8; ++k) {
        float mv = -INFINITY; int mi = 0;
        #pragma unroll
        for (int i = 0; i < 32; ++i)
            if (z[i] > mv) { mv = z[i]; mi = i; }
        sv[t] = mv;
        si[t] = (mi >> 2) * 1024 + t * 4 + (mi & 3);
        __syncthreads();
        for (int s = NT / 2; s > 0; s >>= 1) {
            if (t < s && sv[t + s] > sv[t]) { sv[t] = sv[t + s]; si[t] = si[t + s]; }
            __syncthreads();
        }
        const float gv = sv[0]; const int gd = si[0];
        __syncthreads();
        topv[k] = gv; topd[k] = gd;
        // owner invalidates its element
        if (((gd & 1023) >> 2) == t) z[((gd >> 10) << 2) | (gd & 3)] = -INFINITY;
    }

    // p = softmax over top-8 of z/temp (full-row denominator cancels on renorm)
    float w[8]; float norm = 0.f;
    #pragma unroll
    for (int k = 0; k < 8; ++k) { w[k] = __expf((topv[k] - topv[0]) / temp); norm += w[k]; }
    const float invn = 1.0f / norm;
    #pragma unroll
    for (int k = 0; k < 8; ++k) w[k] *= invn;

    // gather 8 predictor rows: accumulate g = sum_k p_k * P[j_k,:], and lse_k of 10*P[j_k,:]
    float g[32];
    #pragma unroll
    for (int i = 0; i < 32; ++i) g[i] = 0.f;
    float c_acc = 0.f;

    #pragma unroll
    for (int k = 0; k < 8; ++k) {
        const float* prow = pred + (size_t)topd[k] * D;
        const float pk = w[k];
        float s_exp = 0.f;
        #pragma unroll
        for (int i = 0; i < 8; ++i) {
            float4 x = *(const float4*)(prow + i * 1024 + t * 4);
            // values 10*x are bounded (~|1.2|) -> plain sum-exp is exact logsumexp here
            s_exp += __expf(x.x * 10.f) + __expf(x.y * 10.f)
                   + __expf(x.z * 10.f) + __expf(x.w * 10.f);
            g[i*4+0] += pk * x.x;
            g[i*4+1] += pk * x.y;
            g[i*4+2] += pk * x.z;
            g[i*4+3] += pk * x.w;
        }
        const float S = block_sum(s_exp, sv);
        c_acc += pk * __logf(S);
    }

    float* grow = g_ws + (size_t)row * D;
    #pragma unroll
    for (int i = 0; i < 8; ++i) {
        *(float4*)(grow + i * 1024 + t * 4) =
            make_float4(g[i*4+0], g[i*4+1], g[i*4+2], g[i*4+3]);
    }
    if (t == 0) c_ws[row] = c_acc;
}

// ---------- K2: per student row (v>=1): softmax stats + dots with g0/g1, atomic loss ----------
__global__ __launch_bounds__(NT) void k_student(
    const float* __restrict__ student, const float* __restrict__ g_ws,
    const float* __restrict__ c_ws, float* __restrict__ out)
{
    const int row = 256 + blockIdx.x;   // student rows 256..2047
    const int v = row >> 8;             // 1..7
    const int b = row & 255;
    const int t = threadIdx.x;
    __shared__ float sm[NT];

    float y[32];
    const float* srow = student + (size_t)row * D;
    float m = -INFINITY;
    #pragma unroll
    for (int i = 0; i < 8; ++i) {
        float4 x = *(const float4*)(srow + i * 1024 + t * 4);
        y[i*4+0] = x.x * 10.f; y[i*4+1] = x.y * 10.f;
        y[i*4+2] = x.z * 10.f; y[i*4+3] = x.w * 10.f;
        m = fmaxf(m, fmaxf(fmaxf(y[i*4+0], y[i*4+1]), fmaxf(y[i*4+2], y[i*4+3])));
    }
    const float M = block_max(m, sm);

    float zs = 0.f;
    #pragma unroll
    for (int i = 0; i < 32; ++i) { y[i] = __expf(y[i] - M); zs += y[i]; }
    const float Z = block_sum(zs, sm);

    const float* g0 = g_ws + (size_t)b * D;
    const float* g1 = g_ws + (size_t)(256 + b) * D;
    float a0 = 0.f, a1 = 0.f;
    #pragma unroll
    for (int i = 0; i < 8; ++i) {
        float4 gg = *(const float4*)(g0 + i * 1024 + t * 4);
        a0 += y[i*4+0]*gg.x + y[i*4+1]*gg.y + y[i*4+2]*gg.z + y[i*4+3]*gg.w;
    }
    if (v >= 2) {
        #pragma unroll
        for (int i = 0; i < 8; ++i) {
            float4 gg = *(const float4*)(g1 + i * 1024 + t * 4);
            a1 += y[i*4+0]*gg.x + y[i*4+1]*gg.y + y[i*4+2]*gg.z + y[i*4+3]*gg.w;
        }
    }
    a0 = block_sum(a0, sm);
    a1 = block_sum(a1, sm);

    if (t == 0) {
        const float invZ = 1.0f / Z;
        float term = -10.f * a0 * invZ + c_ws[b];
        if (v >= 2) term += -10.f * a1 * invZ + c_ws[256 + b];
        atomicAdd(out, term * (1.0f / 3328.0f));   // 13 pairs * 256 batch
    }
}

// ---------- K3: partial column sums of teacher (16 row-chunks x 8 d-chunks) ----------
__global__ __launch_bounds__(NT) void k_colsum(
    const float* __restrict__ teacher, float* __restrict__ part)
{
    const int rc = blockIdx.x >> 3;     // 0..15, 32 rows each
    const int dc = blockIdx.x & 7;      // 0..7, 1024 cols each
    const int d0 = dc * 1024 + threadIdx.x * 4;
    const float* base = teacher + (size_t)rc * 32 * D + d0;
    float4 acc = make_float4(0.f, 0.f, 0.f, 0.f);
    #pragma unroll 4
    for (int r = 0; r < 32; ++r) {
        float4 x = *(const float4*)(base + (size_t)r * D);
        acc.x += x.x; acc.y += x.y; acc.z += x.z; acc.w += x.w;
    }
    *(float4*)(part + (size_t)rc * D + d0) = acc;
}

// ---------- K4: batch_center finalize, new_center, entropies ----------
__global__ __launch_bounds__(NT) void k_center(
    const float* __restrict__ center, const float* __restrict__ part,
    float* __restrict__ out)
{
    const int t = threadIdx.x;
    __shared__ float sm[NT];
    float c[32], bc[32];
    #pragma unroll
    for (int i = 0; i < 8; ++i) {
        const int d = i * 1024 + t * 4;
        float4 cv = *(const float4*)(center + d);
        float4 s = make_float4(0.f, 0.f, 0.f, 0.f);
        for (int rc = 0; rc < 16; ++rc) {
            float4 p = *(const float4*)(part + (size_t)rc * D + d);
            s.x += p.x; s.y += p.y; s.z += p.z; s.w += p.w;
        }
        const float sc = 1.0f / 512.0f;
        bc[i*4+0] = s.x * sc; bc[i*4+1] = s.y * sc;
        bc[i*4+2] = s.z * sc; bc[i*4+3] = s.w * sc;
        c[i*4+0] = cv.x; c[i*4+1] = cv.y; c[i*4+2] = cv.z; c[i*4+3] = cv.w;
        // new_center (out offset 3 is not 16B-aligned -> scalar stores)
        out[3 + d + 0] = cv.x * 0.9f + bc[i*4+0] * 0.1f;
        out[3 + d + 1] = cv.y * 0.9f + bc[i*4+1] * 0.1f;
        out[3 + d + 2] = cv.z * 0.9f + bc[i*4+2] * 0.1f;
        out[3 + d + 3] = cv.w * 0.9f + bc[i*4+3] * 0.1f;
    }

    float mc = -INFINITY, mb = -INFINITY;
    #pragma unroll
    for (int i = 0; i < 32; ++i) { mc = fmaxf(mc, c[i]); mb = fmaxf(mb, bc[i]); }
    mc = block_max(mc, sm);
    mb = block_max(mb, sm);

    float zc = 0.f, zb = 0.f;
    #pragma unroll
    for (int i = 0; i < 32; ++i) { zc += __expf(c[i] - mc); zb += __expf(bc[i] - mb); }
    zc = block_sum(zc, sm);
    zb = block_sum(zb, sm);
    const float lnZc = __logf(zc);

    float te = 0.f, en = 0.f;
    #pragma unroll
    for (int i = 0; i < 32; ++i) {
        const float lsm = c[i] - mc - lnZc;           // log_softmax(center)
        te += __expf(c[i] - mc) * lsm;                // * softmax(center) (pre /zc)
        en += __expf(bc[i] - mb) * lsm;               // * softmax(batch_center) (pre /zb)
    }
    te = block_sum(te, sm);
    en = block_sum(en, sm);
    if (t == 0) {
        out[1] = en / zb;   // entropy
        out[2] = te / zc;   // true_entropy
    }
}

extern "C" void kernel_launch(void* const* d_in, const int* in_sizes, int n_in,
                              void* d_out, int out_size, void* d_ws, size_t ws_size,
                              hipStream_t stream) {
    const float* student = (const float*)d_in[0];
    const float* teacher = (const float*)d_in[1];
    const float* pred    = (const float*)d_in[2];
    const float* center  = (const float*)d_in[3];
    const int*   epoch   = (const int*)d_in[4];
    float* out = (float*)d_out;

    float* g_ws = (float*)d_ws;                       // 512*8192 floats (16 MB)
    float* c_ws = g_ws + (size_t)512 * D;             // 512 floats
    float* part = c_ws + 512;                         // 16*8192 floats (512 KB)

    hipMemsetAsync(d_out, 0, sizeof(float), stream);  // zero loss accumulator

    k_teacher<<<512, NT, 0, stream>>>(teacher, center, pred, epoch, g_ws, c_ws);
    k_colsum<<<128, NT, 0, stream>>>(teacher, part);
    k_student<<<1792, NT, 0, stream>>>(student, g_ws, c_ws, out);
    k_center<<<1, NT, 0, stream>>>(center, part, out);
}

// Round 2
// 97.111 us; speedup vs baseline: 1.1940x; 1.1940x over previous
//
#include <hip/hip_runtime.h>
#include <hip/hip_bf16.h>
#include <math.h>

#define D 8192
#define NT 256

// ---------- wave (64-lane) shuffle reductions ----------
__device__ __forceinline__ float wave_sum(float v) {
    #pragma unroll
    for (int o = 32; o > 0; o >>= 1) v += __shfl_xor(v, o, 64);
    return v;
}
__device__ __forceinline__ float wave_max(float v) {
    #pragma unroll
    for (int o = 32; o > 0; o >>= 1) v = fmaxf(v, __shfl_xor(v, o, 64));
    return v;
}
// block = 256 threads = 4 waves; sm4 is __shared__ float[4]
__device__ __forceinline__ float block_sum(float v, float* sm4) {
    const int lane = threadIdx.x & 63, w = threadIdx.x >> 6;
    v = wave_sum(v);
    if (lane == 0) sm4[w] = v;
    __syncthreads();
    float r = sm4[0] + sm4[1] + sm4[2] + sm4[3];
    __syncthreads();
    return r;
}
__device__ __forceinline__ float block_max(float v, float* sm4) {
    const int lane = threadIdx.x & 63, w = threadIdx.x >> 6;
    v = wave_max(v);
    if (lane == 0) sm4[w] = v;
    __syncthreads();
    float r = fmaxf(fmaxf(sm4[0], sm4[1]), fmaxf(sm4[2], sm4[3]));
    __syncthreads();
    return r;
}

// ---------- K1a: per teacher row: top-8 indices + renormalized weights ----------
__global__ __launch_bounds__(NT) void k_topk(
    const float* __restrict__ teacher, const float* __restrict__ center,
    const int* __restrict__ epoch_p,
    int* __restrict__ idx_ws, float* __restrict__ p_ws)
{
    const int row = blockIdx.x;     // 0..511
    const int t = threadIdx.x;
    const int lane = t & 63, w = t >> 6;
    __shared__ float svv[4];
    __shared__ int   sii[4];

    const int e = epoch_p[0];
    const float temp = (e < 30) ? (0.04f + 0.03f * (float)e / 29.0f) : 0.07f;

    // z = teacher - center, 32 elems/thread
    float z[32];
    const float* trow = teacher + (size_t)row * D;
    #pragma unroll
    for (int i = 0; i < 8; ++i) {
        const int d = i * 1024 + t * 4;
        float4 tv = *(const float4*)(trow + d);
        float4 cv = *(const float4*)(center + d);
        z[i*4+0] = tv.x - cv.x; z[i*4+1] = tv.y - cv.y;
        z[i*4+2] = tv.z - cv.z; z[i*4+3] = tv.w - cv.w;
    }

    float topv[8]; int topd[8];
    #pragma unroll
    for (int k = 0; k < 8; ++k) {
        // thread-local argmax
        float mv = -INFINITY; int mi = 0;
        #pragma unroll
        for (int i = 0; i < 32; ++i)
            if (z[i] > mv) { mv = z[i]; mi = i; }
        int md = (mi >> 2) * 1024 + t * 4 + (mi & 3);
        // wave argmax via shfl
        #pragma unroll
        for (int o = 32; o > 0; o >>= 1) {
            float ov = __shfl_xor(mv, o, 64);
            int   od = __shfl_xor(md, o, 64);
            if (ov > mv) { mv = ov; md = od; }
        }
        if (lane == 0) { svv[w] = mv; sii[w] = md; }
        __syncthreads();
        float gv = svv[0]; int gd = sii[0];
        #pragma unroll
        for (int j = 1; j < 4; ++j)
            if (svv[j] > gv) { gv = svv[j]; gd = sii[j]; }
        __syncthreads();
        topv[k] = gv; topd[k] = gd;
        if (((gd & 1023) >> 2) == t) z[((gd >> 10) << 2) | (gd & 3)] = -INFINITY;
    }

    if (t < 8) {
        // p = softmax over top-8 of z/temp (row denominator cancels)
        // compute redundantly in 8 threads cheaply via registers? do it in t==0 scalar-style:
    }
    if (t == 0) {
        float wgt[8]; float norm = 0.f;
        #pragma unroll
        for (int k = 0; k < 8; ++k) { wgt[k] = __expf((topv[k] - topv[0]) / temp); norm += wgt[k]; }
        const float invn = 1.0f / norm;
        #pragma unroll
        for (int k = 0; k < 8; ++k) {
            p_ws[row * 8 + k] = wgt[k] * invn;
            idx_ws[row * 8 + k] = topd[k];
        }
    }
}

// ---------- K1b: gather predictor rows, 4 D-chunks per row (2048 blocks) ----------
__global__ __launch_bounds__(NT) void k_gather(
    const float* __restrict__ pred, const int* __restrict__ idx_ws,
    const float* __restrict__ p_ws,
    float* __restrict__ g_ws, float* __restrict__ part_lse)
{
    const int row = blockIdx.x >> 2;   // 0..511
    const int ch  = blockIdx.x & 3;    // 0..3 (2048 cols each)
    const int t = threadIdx.x;
    const int lane = t & 63, w = t >> 6;
    const int d0 = ch * 2048 + t * 4;  // this thread: d0 and d0+1024
    __shared__ float sred[4][8];

    int jk[8]; float pk[8];
    #pragma unroll
    for (int k = 0; k < 8; ++k) {
        jk[k] = idx_ws[row * 8 + k];
        pk[k] = p_ws[row * 8 + k];
    }

    float4 a0 = make_float4(0.f,0.f,0.f,0.f), a1 = make_float4(0.f,0.f,0.f,0.f);
    float se[8];
    #pragma unroll
    for (int k = 0; k < 8; ++k) {
        const float* prow = pred + (size_t)jk[k] * D;
        float4 x0 = *(const float4*)(prow + d0);
        float4 x1 = *(const float4*)(prow + d0 + 1024);
        se[k] = __expf(x0.x*10.f) + __expf(x0.y*10.f) + __expf(x0.z*10.f) + __expf(x0.w*10.f)
              + __expf(x1.x*10.f) + __expf(x1.y*10.f) + __expf(x1.z*10.f) + __expf(x1.w*10.f);
        const float p = pk[k];
        a0.x += p*x0.x; a0.y += p*x0.y; a0.z += p*x0.z; a0.w += p*x0.w;
        a1.x += p*x1.x; a1.y += p*x1.y; a1.z += p*x1.z; a1.w += p*x1.w;
    }
    float* grow = g_ws + (size_t)row * D;
    *(float4*)(grow + d0)        = a0;
    *(float4*)(grow + d0 + 1024) = a1;

    // reduce se[k] over block: wave shfl then 4-entry combine
    #pragma unroll
    for (int k = 0; k < 8; ++k) se[k] = wave_sum(se[k]);
    if (lane == 0) {
        #pragma unroll
        for (int k = 0; k < 8; ++k) sred[w][k] = se[k];
    }
    __syncthreads();
    if (t < 8)
        part_lse[(size_t)blockIdx.x * 8 + t] =
            sred[0][t] + sred[1][t] + sred[2][t] + sred[3][t];
}

// ---------- K1c: finalize c_ws[row] = sum_k p_k * log(sum_chunks) ----------
__global__ void k_finalize(const float* __restrict__ p_ws,
                           const float* __restrict__ part_lse,
                           float* __restrict__ c_ws)
{
    const int r = blockIdx.x * blockDim.x + threadIdx.x;
    if (r >= 512) return;
    float c = 0.f;
    #pragma unroll
    for (int k = 0; k < 8; ++k) {
        float s = part_lse[(size_t)(r*4+0)*8+k] + part_lse[(size_t)(r*4+1)*8+k]
                + part_lse[(size_t)(r*4+2)*8+k] + part_lse[(size_t)(r*4+3)*8+k];
        c += p_ws[r * 8 + k] * __logf(s);
    }
    c_ws[r] = c;
}

// ---------- K2: per student row: softmax stats + dots with g0/g1 ----------
__global__ __launch_bounds__(NT) void k_student(
    const float* __restrict__ student, const float* __restrict__ g_ws,
    const float* __restrict__ c_ws, float* __restrict__ out)
{
    const int row = 256 + blockIdx.x;   // 256..2047
    const int v = row >> 8;             // 1..7
    const int b = row & 255;
    const int t = threadIdx.x;
    __shared__ float sm4[4];

    float y[32];
    const float* srow = student + (size_t)row * D;
    float m = -INFINITY;
    #pragma unroll
    for (int i = 0; i < 8; ++i) {
        float4 x = *(const float4*)(srow + i * 1024 + t * 4);
        y[i*4+0] = x.x * 10.f; y[i*4+1] = x.y * 10.f;
        y[i*4+2] = x.z * 10.f; y[i*4+3] = x.w * 10.f;
        m = fmaxf(m, fmaxf(fmaxf(y[i*4+0], y[i*4+1]), fmaxf(y[i*4+2], y[i*4+3])));
    }
    const float M = block_max(m, sm4);

    float zs = 0.f;
    #pragma unroll
    for (int i = 0; i < 32; ++i) { y[i] = __expf(y[i] - M); zs += y[i]; }

    const float* g0 = g_ws + (size_t)b * D;
    const float* g1 = g_ws + (size_t)(256 + b) * D;
    float a0 = 0.f, a1 = 0.f;
    #pragma unroll
    for (int i = 0; i < 8; ++i) {
        float4 gg = *(const float4*)(g0 + i * 1024 + t * 4);
        a0 += y[i*4+0]*gg.x + y[i*4+1]*gg.y + y[i*4+2]*gg.z + y[i*4+3]*gg.w;
    }
    if (v >= 2) {
        #pragma unroll
        for (int i = 0; i < 8; ++i) {
            float4 gg = *(const float4*)(g1 + i * 1024 + t * 4);
            a1 += y[i*4+0]*gg.x + y[i*4+1]*gg.y + y[i*4+2]*gg.z + y[i*4+3]*gg.w;
        }
    }
    const float Z = block_sum(zs, sm4);
    a0 = block_sum(a0, sm4);
    a1 = block_sum(a1, sm4);

    if (t == 0) {
        const float invZ = 1.0f / Z;
        float term = -10.f * a0 * invZ + c_ws[b];
        if (v >= 2) term += -10.f * a1 * invZ + c_ws[256 + b];
        atomicAdd(out, term * (1.0f / 3328.0f));   // 13 pairs * 256 batch
    }
}

// ---------- K3: partial column sums of teacher ----------
__global__ __launch_bounds__(NT) void k_colsum(
    const float* __restrict__ teacher, float* __restrict__ part)
{
    const int rc = blockIdx.x >> 3;     // 0..15, 32 rows each
    const int dc = blockIdx.x & 7;      // 0..7
    const int d0 = dc * 1024 + threadIdx.x * 4;
    const float* base = teacher + (size_t)rc * 32 * D + d0;
    float4 acc = make_float4(0.f, 0.f, 0.f, 0.f);
    #pragma unroll 4
    for (int r = 0; r < 32; ++r) {
        float4 x = *(const float4*)(base + (size_t)r * D);
        acc.x += x.x; acc.y += x.y; acc.z += x.z; acc.w += x.w;
    }
    *(float4*)(part + (size_t)rc * D + d0) = acc;
}

// ---------- K4: batch_center finalize, new_center, entropies ----------
__global__ __launch_bounds__(NT) void k_center(
    const float* __restrict__ center, const float* __restrict__ part,
    float* __restrict__ out)
{
    const int t = threadIdx.x;
    __shared__ float sm4[4];
    float c[32], bc[32];
    #pragma unroll
    for (int i = 0; i < 8; ++i) {
        const int d = i * 1024 + t * 4;
        float4 cv = *(const float4*)(center + d);
        float4 s = make_float4(0.f, 0.f, 0.f, 0.f);
        for (int rc = 0; rc < 16; ++rc) {
            float4 p = *(const float4*)(part + (size_t)rc * D + d);
            s.x += p.x; s.y += p.y; s.z += p.z; s.w += p.w;
        }
        const float sc = 1.0f / 512.0f;
        bc[i*4+0] = s.x * sc; bc[i*4+1] = s.y * sc;
        bc[i*4+2] = s.z * sc; bc[i*4+3] = s.w * sc;
        c[i*4+0] = cv.x; c[i*4+1] = cv.y; c[i*4+2] = cv.z; c[i*4+3] = cv.w;
        out[3 + d + 0] = cv.x * 0.9f + bc[i*4+0] * 0.1f;
        out[3 + d + 1] = cv.y * 0.9f + bc[i*4+1] * 0.1f;
        out[3 + d + 2] = cv.z * 0.9f + bc[i*4+2] * 0.1f;
        out[3 + d + 3] = cv.w * 0.9f + bc[i*4+3] * 0.1f;
    }

    float mc = -INFINITY, mb = -INFINITY;
    #pragma unroll
    for (int i = 0; i < 32; ++i) { mc = fmaxf(mc, c[i]); mb = fmaxf(mb, bc[i]); }
    mc = block_max(mc, sm4);
    mb = block_max(mb, sm4);

    float zc = 0.f, zb = 0.f;
    #pragma unroll
    for (int i = 0; i < 32; ++i) { zc += __expf(c[i] - mc); zb += __expf(bc[i] - mb); }
    zc = block_sum(zc, sm4);
    zb = block_sum(zb, sm4);
    const float lnZc = __logf(zc);

    float te = 0.f, en = 0.f;
    #pragma unroll
    for (int i = 0; i < 32; ++i) {
        const float lsm = c[i] - mc - lnZc;
        te += __expf(c[i] - mc) * lsm;
        en += __expf(bc[i] - mb) * lsm;
    }
    te = block_sum(te, sm4);
    en = block_sum(en, sm4);
    if (t == 0) {
        out[1] = en / zb;
        out[2] = te / zc;
    }
}

extern "C" void kernel_launch(void* const* d_in, const int* in_sizes, int n_in,
                              void* d_out, int out_size, void* d_ws, size_t ws_size,
                              hipStream_t stream) {
    const float* student = (const float*)d_in[0];
    const float* teacher = (const float*)d_in[1];
    const float* pred    = (const float*)d_in[2];
    const float* center  = (const float*)d_in[3];
    const int*   epoch   = (const int*)d_in[4];
    float* out = (float*)d_out;

    float* g_ws    = (float*)d_ws;                    // 512*8192 f (16 MB)
    float* c_ws    = g_ws + (size_t)512 * D;          // 512 f
    float* part    = c_ws + 512;                      // 16*8192 f (512 KB)
    int*   idx_ws  = (int*)(part + (size_t)16 * D);   // 512*8 i
    float* p_ws    = (float*)(idx_ws + 512 * 8);      // 512*8 f
    float* part_lse= p_ws + 512 * 8;                  // 2048*8 f

    hipMemsetAsync(d_out, 0, sizeof(float), stream);  // zero loss accumulator

    k_topk<<<512, NT, 0, stream>>>(teacher, center, epoch, idx_ws, p_ws);
    k_gather<<<2048, NT, 0, stream>>>(pred, idx_ws, p_ws, g_ws, part_lse);
    k_finalize<<<2, 256, 0, stream>>>(p_ws, part_lse, c_ws);
    k_colsum<<<128, NT, 0, stream>>>(teacher, part);
    k_student<<<1792, NT, 0, stream>>>(student, g_ws, c_ws, out);
    k_center<<<1, NT, 0, stream>>>(center, part, out);
}

// Round 3
// 70.581 us; speedup vs baseline: 1.6428x; 1.3759x over previous
//
#include <hip/hip_runtime.h>
#include <hip/hip_bf16.h>
#include <math.h>

#define D 8192
#define NT 256

// ---------- wave (64-lane) shuffle reductions ----------
__device__ __forceinline__ float wave_sum(float v) {
    #pragma unroll
    for (int o = 32; o > 0; o >>= 1) v += __shfl_xor(v, o, 64);
    return v;
}
__device__ __forceinline__ float wave_max(float v) {
    #pragma unroll
    for (int o = 32; o > 0; o >>= 1) v = fmaxf(v, __shfl_xor(v, o, 64));
    return v;
}

// ================= K1: per teacher row: top-8 + weights (also zeroes out[0]) ==========
__global__ __launch_bounds__(NT) void k_topk(
    const float* __restrict__ teacher, const float* __restrict__ center,
    const int* __restrict__ epoch_p,
    int* __restrict__ idx_ws, float* __restrict__ p_ws, float* __restrict__ out)
{
    const int row = blockIdx.x;     // 0..511
    const int t = threadIdx.x;
    const int lane = t & 63, w = t >> 6;
    __shared__ float svv[8][4];
    __shared__ int   sii[8][4];

    if (row == 0 && t == 0) out[0] = 0.f;   // loss accumulator reset (runs before any adds)

    const int e = epoch_p[0];
    const float temp = (e < 30) ? (0.04f + 0.03f * (float)e / 29.0f) : 0.07f;

    // z = teacher - center, 32 elems/thread
    float z[32];
    const float* trow = teacher + (size_t)row * D;
    #pragma unroll
    for (int i = 0; i < 8; ++i) {
        const int d = i * 1024 + t * 4;
        float4 tv = *(const float4*)(trow + d);
        float4 cv = *(const float4*)(center + d);
        z[i*4+0] = tv.x - cv.x; z[i*4+1] = tv.y - cv.y;
        z[i*4+2] = tv.z - cv.z; z[i*4+3] = tv.w - cv.w;
    }

    // cached thread-local argmax; only popped owner rescans
    float mvl = -INFINITY; int mil = 0;
    #pragma unroll
    for (int i = 0; i < 32; ++i)
        if (z[i] > mvl) { mvl = z[i]; mil = i; }

    float topv[8]; int topd[8];
    #pragma unroll 1
    for (int k = 0; k < 8; ++k) {
        float mv = mvl;
        int md = ((mil >> 2) << 10) + t * 4 + (mil & 3);
        #pragma unroll
        for (int o = 32; o > 0; o >>= 1) {
            float ov = __shfl_xor(mv, o, 64);
            int   od = __shfl_xor(md, o, 64);
            if (ov > mv) { mv = ov; md = od; }
        }
        if (lane == 0) { svv[k][w] = mv; sii[k][w] = md; }
        __syncthreads();
        float gv = svv[k][0]; int gd = sii[k][0];
        #pragma unroll
        for (int j = 1; j < 4; ++j)
            if (svv[k][j] > gv) { gv = svv[k][j]; gd = sii[k][j]; }
        topv[k] = gv; topd[k] = gd;
        if (((gd & 1023) >> 2) == t) {
            z[((gd >> 10) << 2) | (gd & 3)] = -INFINITY;
            mvl = -INFINITY; mil = 0;
            #pragma unroll
            for (int i = 0; i < 32; ++i)
                if (z[i] > mvl) { mvl = z[i]; mil = i; }
        }
    }

    if (t == 0) {
        float wgt[8]; float norm = 0.f;
        #pragma unroll
        for (int k = 0; k < 8; ++k) { wgt[k] = __expf((topv[k] - topv[0]) / temp); norm += wgt[k]; }
        const float invn = 1.0f / norm;
        #pragma unroll
        for (int k = 0; k < 8; ++k) {
            p_ws[row * 8 + k] = wgt[k] * invn;
            idx_ws[row * 8 + k] = topd[k];
        }
    }
}

// ========= K2: gather predictor rows (blocks 0..2047) + teacher colsum (2048..2175) =====
__global__ __launch_bounds__(NT) void k_gather_colsum(
    const float* __restrict__ pred, const int* __restrict__ idx_ws,
    const float* __restrict__ p_ws, const float* __restrict__ teacher,
    float* __restrict__ g_ws, float* __restrict__ part_lse, float* __restrict__ part)
{
    const int bid = blockIdx.x;
    const int t = threadIdx.x;

    if (bid >= 2048) {
        // ---- colsum role ----
        const int cb = bid - 2048;
        const int rc = cb >> 3, dc = cb & 7;
        const int d0 = dc * 1024 + t * 4;
        const float* base = teacher + (size_t)rc * 32 * D + d0;
        float4 acc = make_float4(0.f, 0.f, 0.f, 0.f);
        #pragma unroll 4
        for (int r = 0; r < 32; ++r) {
            float4 x = *(const float4*)(base + (size_t)r * D);
            acc.x += x.x; acc.y += x.y; acc.z += x.z; acc.w += x.w;
        }
        *(float4*)(part + (size_t)rc * D + d0) = acc;
        return;
    }

    // ---- gather role ----
    const int row = bid >> 2;          // 0..511
    const int ch  = bid & 3;           // 0..3
    const int lane = t & 63, w = t >> 6;
    const int d0 = ch * 2048 + t * 4;
    __shared__ float sred[4][8];

    int jk[8]; float pk[8];
    #pragma unroll
    for (int k = 0; k < 8; ++k) {
        jk[k] = idx_ws[row * 8 + k];
        pk[k] = p_ws[row * 8 + k];
    }

    float4 a0 = make_float4(0.f,0.f,0.f,0.f), a1 = make_float4(0.f,0.f,0.f,0.f);
    float se[8];
    #pragma unroll
    for (int k = 0; k < 8; ++k) {
        const float* prow = pred + (size_t)jk[k] * D;
        float4 x0 = *(const float4*)(prow + d0);
        float4 x1 = *(const float4*)(prow + d0 + 1024);
        se[k] = __expf(x0.x*10.f) + __expf(x0.y*10.f) + __expf(x0.z*10.f) + __expf(x0.w*10.f)
              + __expf(x1.x*10.f) + __expf(x1.y*10.f) + __expf(x1.z*10.f) + __expf(x1.w*10.f);
        const float p = pk[k];
        a0.x += p*x0.x; a0.y += p*x0.y; a0.z += p*x0.z; a0.w += p*x0.w;
        a1.x += p*x1.x; a1.y += p*x1.y; a1.z += p*x1.z; a1.w += p*x1.w;
    }
    float* grow = g_ws + (size_t)row * D;
    *(float4*)(grow + d0)        = a0;
    *(float4*)(grow + d0 + 1024) = a1;

    #pragma unroll
    for (int k = 0; k < 8; ++k) se[k] = wave_sum(se[k]);
    if (lane == 0) {
        #pragma unroll
        for (int k = 0; k < 8; ++k) sred[w][k] = se[k];
    }
    __syncthreads();
    if (t < 8)
        part_lse[(size_t)bid * 8 + t] =
            sred[0][t] + sred[1][t] + sred[2][t] + sred[3][t];
}

// ==== K3: blocks 0,1 = c-term finalize->atomic loss; block 2 = center; 3.. = student ====
__global__ __launch_bounds__(NT) void k_main(
    const float* __restrict__ student, const float* __restrict__ g_ws,
    const float* __restrict__ p_ws, const float* __restrict__ part_lse,
    const float* __restrict__ part, const float* __restrict__ center,
    float* __restrict__ out)
{
    const int bid = blockIdx.x;
    const int t = threadIdx.x;
    const int lane = t & 63, w = t >> 6;

    if (bid < 2) {
        // ---- c-term finalize: r = bid*256 + t; pair multiplicity 7 (iq=0) or 6 (iq=1) ----
        __shared__ float sm4[4];
        const int r = (bid << 8) | t;
        float c = 0.f;
        #pragma unroll
        for (int k = 0; k < 8; ++k) {
            float s = part_lse[(size_t)(r*4+0)*8+k] + part_lse[(size_t)(r*4+1)*8+k]
                    + part_lse[(size_t)(r*4+2)*8+k] + part_lse[(size_t)(r*4+3)*8+k];
            c += p_ws[r * 8 + k] * __logf(s);
        }
        const float wgt = (bid == 0) ? 7.0f : 6.0f;
        float vv = wave_sum(c * wgt * (1.0f / 3328.0f));
        if (lane == 0) sm4[w] = vv;
        __syncthreads();
        if (t == 0) atomicAdd(out, sm4[0] + sm4[1] + sm4[2] + sm4[3]);
        return;
    }

    if (bid == 2) {
        // ---- center: batch_center, EMA, entropies ----
        __shared__ float sm4[4];
        float c[32], bc[32];
        #pragma unroll
        for (int i = 0; i < 8; ++i) {
            const int d = i * 1024 + t * 4;
            float4 cv = *(const float4*)(center + d);
            float4 s = make_float4(0.f, 0.f, 0.f, 0.f);
            for (int rc = 0; rc < 16; ++rc) {
                float4 p = *(const float4*)(part + (size_t)rc * D + d);
                s.x += p.x; s.y += p.y; s.z += p.z; s.w += p.w;
            }
            const float sc = 1.0f / 512.0f;
            bc[i*4+0] = s.x * sc; bc[i*4+1] = s.y * sc;
            bc[i*4+2] = s.z * sc; bc[i*4+3] = s.w * sc;
            c[i*4+0] = cv.x; c[i*4+1] = cv.y; c[i*4+2] = cv.z; c[i*4+3] = cv.w;
            out[3 + d + 0] = cv.x * 0.9f + bc[i*4+0] * 0.1f;
            out[3 + d + 1] = cv.y * 0.9f + bc[i*4+1] * 0.1f;
            out[3 + d + 2] = cv.z * 0.9f + bc[i*4+2] * 0.1f;
            out[3 + d + 3] = cv.w * 0.9f + bc[i*4+3] * 0.1f;
        }

        float mc = -INFINITY, mb = -INFINITY;
        #pragma unroll
        for (int i = 0; i < 32; ++i) { mc = fmaxf(mc, c[i]); mb = fmaxf(mb, bc[i]); }
        mc = wave_max(mc); mb = wave_max(mb);
        if (lane == 0) sm4[w] = mc;
        __syncthreads();
        mc = fmaxf(fmaxf(sm4[0], sm4[1]), fmaxf(sm4[2], sm4[3]));
        __syncthreads();
        if (lane == 0) sm4[w] = mb;
        __syncthreads();
        mb = fmaxf(fmaxf(sm4[0], sm4[1]), fmaxf(sm4[2], sm4[3]));
        __syncthreads();

        float zc = 0.f, zb = 0.f;
        #pragma unroll
        for (int i = 0; i < 32; ++i) { zc += __expf(c[i] - mc); zb += __expf(bc[i] - mb); }
        zc = wave_sum(zc); zb = wave_sum(zb);
        if (lane == 0) sm4[w] = zc;
        __syncthreads();
        zc = sm4[0] + sm4[1] + sm4[2] + sm4[3];
        __syncthreads();
        if (lane == 0) sm4[w] = zb;
        __syncthreads();
        zb = sm4[0] + sm4[1] + sm4[2] + sm4[3];
        __syncthreads();
        const float lnZc = __logf(zc);

        float te = 0.f, en = 0.f;
        #pragma unroll
        for (int i = 0; i < 32; ++i) {
            const float lsm = c[i] - mc - lnZc;
            te += __expf(c[i] - mc) * lsm;
            en += __expf(bc[i] - mb) * lsm;
        }
        te = wave_sum(te); en = wave_sum(en);
        if (lane == 0) sm4[w] = te;
        __syncthreads();
        te = sm4[0] + sm4[1] + sm4[2] + sm4[3];
        __syncthreads();
        if (lane == 0) sm4[w] = en;
        __syncthreads();
        en = sm4[0] + sm4[1] + sm4[2] + sm4[3];
        if (t == 0) {
            out[1] = en / zb;
            out[2] = te / zc;
        }
        return;
    }

    // ---- student role: rows 256..2047 ----
    __shared__ float smax[4];
    __shared__ float sred3[4][3];
    const int row = 256 + (bid - 3);
    const int v = row >> 8;             // 1..7
    const int b = row & 255;

    float y[32];
    const float* srow = student + (size_t)row * D;
    float m = -INFINITY;
    #pragma unroll
    for (int i = 0; i < 8; ++i) {
        float4 x = *(const float4*)(srow + i * 1024 + t * 4);
        y[i*4+0] = x.x * 10.f; y[i*4+1] = x.y * 10.f;
        y[i*4+2] = x.z * 10.f; y[i*4+3] = x.w * 10.f;
        m = fmaxf(m, fmaxf(fmaxf(y[i*4+0], y[i*4+1]), fmaxf(y[i*4+2], y[i*4+3])));
    }
    m = wave_max(m);
    if (lane == 0) smax[w] = m;
    __syncthreads();
    const float M = fmaxf(fmaxf(smax[0], smax[1]), fmaxf(smax[2], smax[3]));

    float zs = 0.f;
    #pragma unroll
    for (int i = 0; i < 32; ++i) { y[i] = __expf(y[i] - M); zs += y[i]; }

    const float* g0 = g_ws + (size_t)b * D;
    const float* g1 = g_ws + (size_t)(256 + b) * D;
    float a0 = 0.f, a1 = 0.f;
    #pragma unroll
    for (int i = 0; i < 8; ++i) {
        float4 gg = *(const float4*)(g0 + i * 1024 + t * 4);
        a0 += y[i*4+0]*gg.x + y[i*4+1]*gg.y + y[i*4+2]*gg.z + y[i*4+3]*gg.w;
    }
    if (v >= 2) {
        #pragma unroll
        for (int i = 0; i < 8; ++i) {
            float4 gg = *(const float4*)(g1 + i * 1024 + t * 4);
            a1 += y[i*4+0]*gg.x + y[i*4+1]*gg.y + y[i*4+2]*gg.z + y[i*4+3]*gg.w;
        }
    }
    zs = wave_sum(zs); a0 = wave_sum(a0); a1 = wave_sum(a1);
    if (lane == 0) { sred3[w][0] = zs; sred3[w][1] = a0; sred3[w][2] = a1; }
    __syncthreads();
    if (t == 0) {
        const float Z  = sred3[0][0] + sred3[1][0] + sred3[2][0] + sred3[3][0];
        const float A0 = sred3[0][1] + sred3[1][1] + sred3[2][1] + sred3[3][1];
        const float A1 = sred3[0][2] + sred3[1][2] + sred3[2][2] + sred3[3][2];
        const float invZ = 1.0f / Z;
        float term = -10.f * A0 * invZ;
        if (v >= 2) term += -10.f * A1 * invZ;
        atomicAdd(out, term * (1.0f / 3328.0f));
    }
}

extern "C" void kernel_launch(void* const* d_in, const int* in_sizes, int n_in,
                              void* d_out, int out_size, void* d_ws, size_t ws_size,
                              hipStream_t stream) {
    const float* student = (const float*)d_in[0];
    const float* teacher = (const float*)d_in[1];
    const float* pred    = (const float*)d_in[2];
    const float* center  = (const float*)d_in[3];
    const int*   epoch   = (const int*)d_in[4];
    float* out = (float*)d_out;

    float* g_ws    = (float*)d_ws;                    // 512*8192 f (16 MB)
    float* part    = g_ws + (size_t)512 * D;          // 16*8192 f (512 KB)
    int*   idx_ws  = (int*)(part + (size_t)16 * D);   // 512*8 i
    float* p_ws    = (float*)(idx_ws + 512 * 8);      // 512*8 f
    float* part_lse= p_ws + 512 * 8;                  // 2048*8 f

    k_topk<<<512, NT, 0, stream>>>(teacher, center, epoch, idx_ws, p_ws, out);
    k_gather_colsum<<<2176, NT, 0, stream>>>(pred, idx_ws, p_ws, teacher,
                                             g_ws, part_lse, part);
    k_main<<<1795, NT, 0, stream>>>(student, g_ws, p_ws, part_lse, part, center, out);
}